// Round 1
// 181.788 us; speedup vs baseline: 1.2115x; 1.2115x over previous
//
#include <hip/hip_runtime.h>
#include <stdint.h>

// Problem constants
#define NROWS 16384   // B*H*W = 16*32*32
#define KENT  8192    // codebook entries
#define CDIM  256     // embedding dim
#define NELEM 4194304 // B*H*W*C elements of z / z_q

// int8 screen scales: z*22 (clamp +-127 = 5.77 sigma), cb*127*8192 (<=0.5 LSB)
#define ZSCALE 22.0f
#define ESCALE 1040384.0f      // 127*8192, exact in fp32
#define MARGIN_INT 4096        // = 1.79e-4 real ~ 8 sigma of i8-quant error
#define SBIAS 4194304          // 1<<22, |score| <= 256*127*127 = 4129024 < SBIAS

// ws layout (bytes), total 23,330,816 (~22.25 MiB):
//   [0,        4194304): zbi8   i8[4M]   z int8, k-major tile layout
//   [4194304,  6291456): cbi8   i8[2M]   codebook int8, same layout
//   [6291456, 23068672): gstats u64[128][16384]  per (64-col group, row):
//                        (top1 << 32) | top2, packed (score+SBIAS)<<6 | col6
//   [23068672,23134208): z2w   float[16384]  np-tree row norms
//   [23134208,23199744): idx   int[16384]

typedef int v4i __attribute__((ext_vector_type(4)));

__device__ inline int q8(float x, float s) {
    int v = __float2int_rn(x * s);
    return v < -127 ? -127 : (v > 127 ? 127 : v);
}
__device__ inline unsigned pk4(int a, int b, int c, int d) {
    return (a & 255) | ((b & 255) << 8) | ((c & 255) << 16) | ((d & 255) << 24);
}
__device__ inline unsigned umax(unsigned a, unsigned b) { return a > b ? a : b; }
__device__ inline unsigned umin(unsigned a, unsigned b) { return a < b ? a : b; }
__device__ inline void gload_lds16(const void* g, void* l) {
    __builtin_amdgcn_global_load_lds(
        (const __attribute__((address_space(1))) void*)g,
        (__attribute__((address_space(3))) void*)l, 16, 0, 0);
}

// ---------------------------------------------------------------------------
// Fused prep: blocks 0..255 = prep_z (VALIDATED np-tree z2 + i8 tile store),
// blocks 256..319 = prep_cb (i8), plus loss init. (gmax/cnt machinery removed)
__global__ __launch_bounds__(128) void vq_prep(
        const float* __restrict__ z, const float* __restrict__ cb,
        float* __restrict__ z2w, char* __restrict__ zbi8,
        char* __restrict__ cbbi8, float* __restrict__ loss_out) {
    const int t = threadIdx.x;
    const int bid = blockIdx.x;

    if (bid >= 256) {   // ---- prep_cb: panel p, one codebook row per thread
        const int p = bid - 256, n0 = p * 128;
        char* dst = cbbi8 + p * 32768;
        const float* src = cb + (n0 + t) * 256;
#pragma unroll
        for (int q = 0; q < 16; ++q) {
            float4 a = *(const float4*)(src + q * 16);
            float4 b = *(const float4*)(src + q * 16 + 4);
            float4 c = *(const float4*)(src + q * 16 + 8);
            float4 d = *(const float4*)(src + q * 16 + 12);
            uint4 v;
            v.x = pk4(q8(a.x,ESCALE), q8(a.y,ESCALE), q8(a.z,ESCALE), q8(a.w,ESCALE));
            v.y = pk4(q8(b.x,ESCALE), q8(b.y,ESCALE), q8(b.z,ESCALE), q8(b.w,ESCALE));
            v.z = pk4(q8(c.x,ESCALE), q8(c.y,ESCALE), q8(c.z,ESCALE), q8(c.w,ESCALE));
            v.w = pk4(q8(d.x,ESCALE), q8(d.y,ESCALE), q8(d.z,ESCALE), q8(d.w,ESCALE));
            *(uint4*)&dst[(q * 128 + t) * 16] = v;
        }
        if (p == 0 && t == 0) loss_out[0] = 0.f;
        return;
    }

    // ---- prep_z: 2 threads/row, one per 128-c half of the np tree
    __shared__ float s64[64];
    const int r = t & 63;
    const int blk = t >> 6;
    const int n = bid * 64 + r;
    const int b = n >> 10, hw = n & 1023;
    const float* base = z + b * 262144 + hw;

    const int p = n >> 7, rp = n & 127;
    char* dst = zbi8 + p * 32768;

    float t0[16], p01[16], p0123[16], C[16];

#pragma unroll
    for (int j = 0; j < 8; ++j) {
        float a[16];
#pragma unroll
        for (int L = 0; L < 16; ++L)
            a[L] = base[(blk * 128 + L + 16 * j) * 1024];
        int qb[16];
#pragma unroll
        for (int L = 0; L < 16; ++L) {
            qb[L] = q8(a[L], ZSCALE);
            float sq = a[L] * a[L];
            asm volatile("" : "+v"(sq));   // forbid FMA contraction into adds
            // np tree phases: C = ((q0+q1)+(q2+q3)) + ((q4+q5)+(q6+q7))
            if (j == 0 || j == 2 || j == 4 || j == 6) t0[L] = sq;
            else if (j == 1) p01[L] = t0[L] + sq;
            else if (j == 3) p0123[L] = p01[L] + (t0[L] + sq);
            else if (j == 5) p01[L] = t0[L] + sq;                 // p45
            else             C[L] = p0123[L] + (p01[L] + (t0[L] + sq));
        }
        uint4 v;
        v.x = pk4(qb[0], qb[1], qb[2], qb[3]);
        v.y = pk4(qb[4], qb[5], qb[6], qb[7]);
        v.z = pk4(qb[8], qb[9], qb[10], qb[11]);
        v.w = pk4(qb[12], qb[13], qb[14], qb[15]);
        *(uint4*)&dst[((blk * 8 + j) * 128 + rp) * 16] = v;
    }
    float t8[8];
#pragma unroll
    for (int L = 0; L < 8; ++L) t8[L] = C[L] + C[L + 8];
    float t4[4];
#pragma unroll
    for (int L = 0; L < 4; ++L) t4[L] = t8[L] + t8[L + 4];
    float t2a = t4[0] + t4[2];
    float t2b = t4[1] + t4[3];
    float bs = t2a + t2b;

    if (blk == 1) s64[r] = bs;
    __syncthreads();
    if (blk == 0) z2w[n] = bs + s64[r];
}

// ---------------------------------------------------------------------------
// int8 MFMA screen v6: same K-loop as v5 (whole A panel in LDS, ONE staging
// drain, B streamed from L2 with 1-deep prefetch). NEW epilogue: per-wave
// streaming top-2 per (row, 64-col group) via shfl butterfly -- no global
// atomics, no post-loop barriers, no LDS candidate machinery. One coalesced
// 8B stat per (row,group) replaces 22MB of scattered atomic traffic.
__global__ __launch_bounds__(256, 4) void vq_gemm(
        const char* __restrict__ zbi8,
        const char* __restrict__ cbbi8,
        unsigned long long* __restrict__ gstats) {
    __shared__ __align__(16) char smem[32768];   // A panel only

    const int tid = threadIdx.x;
    const int w = tid >> 6, l = tid & 63;
    const int q4 = l >> 4, cl = l & 15;
    const int mw = w & 1, nw = w >> 1;

    // XCD-locality swizzle (validated r5): 16 pm x phased 16 pn per XCD
    const unsigned bx = blockIdx.x;
    const unsigned xcd = bx & 7, local = bx >> 3;
    const unsigned png = local >> 8;
    const unsigned rem = local & 255;
    const unsigned pm = (rem >> 4) * 8 + xcd;
    const unsigned pn = png * 16 + (rem & 15);
    const int n0 = pm * 128;

    const char* Ab = zbi8 + pm * 32768;
    const char* Bb = cbbi8 + pn * 32768;

    // stage whole A panel: 8 issues x 256 thr x 16B = 32KB
#pragma unroll
    for (int u = 0; u < 8; ++u)
        gload_lds16(Ab + u * 4096 + tid * 16, smem + u * 4096 + (w << 10));

    // B: per-lane contiguous 16B fragments from L2; j via imm offset, kt via +8192
    const char* bbase = Bb + (q4 * 128 + nw * 64 + cl) * 16;
    v4i bf[4], bfn[4];
#pragma unroll
    for (int j = 0; j < 4; ++j)
        bf[j] = *(const v4i*)(bbase + j * 256);

    v4i acc[4][4];
#pragma unroll
    for (int i = 0; i < 4; ++i)
#pragma unroll
        for (int j = 0; j < 4; ++j) acc[i][j] = (v4i)0;

    __syncthreads();   // single A-staging drain (bf loads ride along)

#pragma unroll
    for (int kt = 0; kt < 4; ++kt) {
        v4i af[4];
#pragma unroll
        for (int i = 0; i < 4; ++i)
            af[i] = *(const v4i*)(smem +
                ((kt * 4 + q4) * 128 + mw * 64 + i * 16 + cl) * 16);
        if (kt < 3) {
#pragma unroll
            for (int j = 0; j < 4; ++j)
                bfn[j] = *(const v4i*)(bbase + (kt + 1) * 8192 + j * 256);
        }
#pragma unroll
        for (int i = 0; i < 4; ++i)
#pragma unroll
            for (int j = 0; j < 4; ++j)
                acc[i][j] = __builtin_amdgcn_mfma_i32_16x16x64_i8(
                    af[i], bf[j], acc[i][j], 0, 0, 0);
#pragma unroll
        for (int j = 0; j < 4; ++j) bf[j] = bfn[j];
    }

    // ---- epilogue: packed top-2 of this wave's 64 cols, per row -----------
    // C layout (16x16 MFMA): col = cl, row(frag i) = q4*4 + g.
    // pack = (score + SBIAS) << 6 | col6   (unsigned-monotone in score)
    unsigned long long* gs = gstats + ((unsigned)(pn * 2 + nw)) * 16384u
                                    + (unsigned)(n0 + mw * 64);
#pragma unroll
    for (int i = 0; i < 4; ++i) {
#pragma unroll
        for (int g = 0; g < 4; ++g) {
            unsigned q0 = ((unsigned)(acc[i][0][g] + SBIAS) << 6) | (unsigned)(cl);
            unsigned q1 = ((unsigned)(acc[i][1][g] + SBIAS) << 6) | (unsigned)(16 + cl);
            unsigned q2 = ((unsigned)(acc[i][2][g] + SBIAS) << 6) | (unsigned)(32 + cl);
            unsigned q3 = ((unsigned)(acc[i][3][g] + SBIAS) << 6) | (unsigned)(48 + cl);
            unsigned a  = umax(q0, q1), b2 = umin(q0, q1);
            unsigned c  = umax(q2, q3), d2 = umin(q2, q3);
            unsigned m1 = umax(a, c);
            unsigned m2 = umax(umin(a, c), umax(b2, d2));
#pragma unroll
            for (int off = 1; off < 16; off <<= 1) {
                unsigned o1 = (unsigned)__shfl_xor((int)m1, off);
                unsigned o2 = (unsigned)__shfl_xor((int)m2, off);
                unsigned mn = umin(m1, o1);
                m1 = umax(m1, o1);
                m2 = umax(mn, umax(m2, o2));
            }
            if (cl == 0)
                gs[i * 16 + q4 * 4 + g] =
                    ((unsigned long long)m1 << 32) | (unsigned long long)m2;
        }
    }
}

// ---------------------------------------------------------------------------
// Exact rescore + finalize (v2): derive per-row global max from gstats top1s,
// gather candidates >= max - MARGIN (group top-1/top-2), then the VALIDATED
// exact fp32 serial-FMA chain; lowest-index ties via packed u64.
// 256 blocks x 64 rows (was 128 x 128 -- half the GPU sat idle).
__global__ __launch_bounds__(256) void vq_rescore(
        const float* __restrict__ z, const float* __restrict__ cb,
        const float* __restrict__ z2w,
        const unsigned long long* __restrict__ gstats,
        int* __restrict__ idx, float* __restrict__ out_idx) {
    __shared__ float zs[32][64];
    __shared__ int thrL[64];
    __shared__ unsigned pmax[4][64];
    __shared__ unsigned candL[512];    // (r<<13)|k
    __shared__ unsigned blkcnt;
    __shared__ unsigned long long bestL[64];

    const int t = threadIdx.x;
    const int n0 = blockIdx.x * 64;
    const int b = n0 >> 10, hw0 = n0 & 1023;
    const int r = t & 63, gc = t >> 6;

    // phase 1: per-row max of group top1s (= exact global row max)
    const unsigned long long* gp =
        gstats + (size_t)(gc * 32) * 16384u + (unsigned)(n0 + r);
    unsigned m = 0;
#pragma unroll 8
    for (int g2 = 0; g2 < 32; ++g2)
        m = umax(m, (unsigned)(gp[(size_t)g2 * 16384u] >> 32));
    pmax[gc][r] = m;
    if (t == 0) blkcnt = 0;
    __syncthreads();
    if (t < 64) {
        unsigned mm = umax(umax(pmax[0][t], pmax[1][t]),
                           umax(pmax[2][t], pmax[3][t]));
        thrL[t] = (int)(mm >> 6) - MARGIN_INT;   // biased domain on both sides
        bestL[t] = ~0ull;
    }
    __syncthreads();

    // phase 2: candidates = group top-1/top-2 entries >= threshold
    {
        int th = thrL[r];
#pragma unroll 4
        for (int g2 = 0; g2 < 32; ++g2) {
            unsigned long long e = gp[(size_t)g2 * 16384u];
            unsigned p1 = (unsigned)(e >> 32), p2 = (unsigned)e;
            unsigned g = (unsigned)(gc * 32 + g2);
            if ((int)(p1 >> 6) >= th) {
                unsigned pos = atomicAdd(&blkcnt, 1u);
                if (pos < 512u)
                    candL[pos] = ((unsigned)r << 13) | (g << 6) | (p1 & 63u);
            }
            if ((int)(p2 >> 6) >= th) {
                unsigned pos = atomicAdd(&blkcnt, 1u);
                if (pos < 512u)
                    candL[pos] = ((unsigned)r << 13) | (g << 6) | (p2 & 63u);
            }
        }
    }
    __syncthreads();
    int ns = (int)(blkcnt < 512u ? blkcnt : 512u);

    for (int base = 0; base < ns; base += 256) {
        bool active = base + t < ns;
        int rr0 = 0, k = 0;
        if (active) {
            unsigned v = candL[base + t];
            rr0 = v >> 13; k = v & 8191;
        }
        float sacc = 0.f;
        for (int ch = 0; ch < 8; ++ch) {
            __syncthreads();
            {   // stage 32 channels x 64 rows, coalesced
                int rr = t & 63, cc2 = t >> 6;
#pragma unroll
                for (int u = 0; u < 8; ++u) {
                    int cc = u * 4 + cc2;
                    zs[cc][rr] = z[b * 262144 + (ch * 32 + cc) * 1024 + hw0 + rr];
                }
            }
            __syncthreads();
            if (active) {
                const float4* cbp = (const float4*)(cb + k * 256 + ch * 32);
                float4 A0 = cbp[0], A1 = cbp[1], A2 = cbp[2], A3 = cbp[3];
                float4 A4 = cbp[4], A5 = cbp[5], A6 = cbp[6], A7 = cbp[7];
                float Af[32] = {A0.x,A0.y,A0.z,A0.w, A1.x,A1.y,A1.z,A1.w,
                                A2.x,A2.y,A2.z,A2.w, A3.x,A3.y,A3.z,A3.w,
                                A4.x,A4.y,A4.z,A4.w, A5.x,A5.y,A5.z,A5.w,
                                A6.x,A6.y,A6.z,A6.w, A7.x,A7.y,A7.z,A7.w};
#pragma unroll
                for (int u = 0; u < 32; ++u)
                    sacc = __builtin_fmaf(zs[u][rr0], Af[u], sacc);
            }
        }
        if (active) {
            float d = z2w[n0 + rr0] - 2.0f * sacc;   // single rounding, d > 0
            unsigned long long key =
                ((unsigned long long)__float_as_uint(d) << 32) | (unsigned)k;
            atomicMin(&bestL[rr0], key);
        }
    }
    __syncthreads();
    if (t < 64) {
        int k = (int)(unsigned)(bestL[t] & 0xFFFFFFFFu);
        idx[n0 + t] = k;
        out_idx[n0 + t] = (float)k;
    }
}

// ---------------------------------------------------------------------------
// Scatter v2, block = (b, j): cb rows gathered ROW-CONTIGUOUSLY (no 16x
// over-fetch) into an LDS tile, out written k-coalesced via LDS transpose.
// out[b,i,j,k] = cb[idx[b*1024+j*32+(k>>3)]][(k&7)*32+i]. No z, no loss here.
__global__ __launch_bounds__(256) void vq_scatter_out(
        const float* __restrict__ cb, const int* __restrict__ idx,
        float* __restrict__ out) {
    __shared__ float tile[32 * 257];   // [w][c], stride 257 floats
    __shared__ int idxs[32];

    const int t = threadIdx.x;
    const int b = blockIdx.x >> 5, j = blockIdx.x & 31;

    if (t < 32) idxs[t] = idx[b * 1024 + j * 32 + t];
    __syncthreads();

    {   // stage: wave reads 64 consecutive c of one cb row (coalesced)
        const int c0 = t & 63;
        const int w0 = (t >> 6) * 8;
#pragma unroll
        for (int it = 0; it < 8; ++it) {
            int w = w0 + it;
            const float* src = cb + idxs[w] * 256 + c0;
            float* drow = tile + w * 257 + c0;
            drow[0]   = src[0];
            drow[64]  = src[64];
            drow[128] = src[128];
            drow[192] = src[192];
        }
    }
    __syncthreads();

    float* obase = out + b * 262144 + j * 256;
    const int wv = t >> 3, cb8 = (t & 7) * 32;
#pragma unroll
    for (int it = 0; it < 32; ++it)     // it = i; lane = k (coalesced store)
        obase[it * 8192 + t] = tile[wv * 257 + cb8 + it];
}

// ---------------------------------------------------------------------------
// Loss, block = (b, i): z read w-coalesced (staged), out re-read coalesced.
// loss += 1.25/N * sum((zp - zq)^2);  zp(o) = z[b,k,i,j], zq(o) = out[o].
__global__ __launch_bounds__(256) void vq_loss(
        const float* __restrict__ z, const float* __restrict__ out,
        float* __restrict__ loss_out) {
    __shared__ float zs[256][33];
    __shared__ float wsum[4];

    const int t = threadIdx.x;
    const int b = blockIdx.x >> 5, i = blockIdx.x & 31;

#pragma unroll
    for (int it = 0; it < 32; ++it) {
        int k = it * 8 + (t >> 5);
        zs[k][t & 31] = z[b * 262144 + k * 1024 + i * 32 + (t & 31)];
    }
    __syncthreads();

    const float* ob = out + b * 262144 + i * 8192;
    float lsum = 0.f;
#pragma unroll 4
    for (int it = 0; it < 32; ++it) {   // it = j; lane = k
        float d = zs[t][it] - ob[it * 256 + t];
        lsum = __builtin_fmaf(d, d, lsum);
    }
#pragma unroll
    for (int off = 32; off >= 1; off >>= 1) lsum += __shfl_down(lsum, off, 64);
    int lane = t & 63, wv = t >> 6;
    if (lane == 0) wsum[wv] = lsum;
    __syncthreads();
    if (t == 0)
        atomicAdd(loss_out, (wsum[0] + wsum[1] + wsum[2] + wsum[3]) *
                            (1.25f / (float)NELEM));
}

// ---------------------------------------------------------------------------
extern "C" void kernel_launch(void* const* d_in, const int* in_sizes, int n_in,
                              void* d_out, int out_size, void* d_ws, size_t ws_size,
                              hipStream_t stream) {
    const float* z  = (const float*)d_in[0];
    const float* cb = (const float*)d_in[1];
    float* out = (float*)d_out;

    char* ws = (char*)d_ws;
    char* zbi8               = ws;                                   // 4 MB
    char* cbbi8              = ws + 4194304;                         // 2 MB
    unsigned long long* gstats = (unsigned long long*)(ws + 6291456); // 16 MB
    float* z2w               = (float*)(ws + 23068672);
    int*   idx               = (int*)(ws + 23134208);

    vq_prep<<<320, 128, 0, stream>>>(z, cb, z2w, zbi8, cbbi8, out + NELEM);

    vq_gemm<<<8192, 256, 0, stream>>>(zbi8, cbbi8, gstats);

    vq_rescore<<<NROWS / 64, 256, 0, stream>>>(z, cb, z2w, gstats,
                                               idx, out + NELEM + 1);

    vq_scatter_out<<<512, 256, 0, stream>>>(cb, idx, out);

    vq_loss<<<512, 256, 0, stream>>>(z, out, out + NELEM);
}